// Round 1
// baseline (1840.229 us; speedup 1.0000x reference)
//
#include <hip/hip_runtime.h>

// Problem constants (match reference setup_inputs).
#define NN 100000      // nodes per ntype
#define EE 500000      // edges per etype
#define DD 64          // embed dim
#define ND (NN * DD)   // floats per ntype output plane

// ---------------------------------------------------------------------------
// Kernel 1: out[2][N][64] = broadcast bias (harness poisons d_out each call).
// float4-vectorized; bias is 64 floats = 16 float4, index = i & 15.
// ---------------------------------------------------------------------------
__global__ void init_bias_kernel(float4* __restrict__ out,
                                 const float4* __restrict__ bias4,
                                 int n4) {
    int i = blockIdx.x * blockDim.x + threadIdx.x;
    if (i < n4) {
        out[i] = bias4[i & 15];
    }
}

// ---------------------------------------------------------------------------
// Kernel 2: fused scatter-add over all 4 relations.
// Each edge is handled by 16 consecutive lanes (16 lanes x float4 = 64 floats).
// Global thread t: rel-edge index = t>>4, lane = t&15.
// Relation mapping (reference):
//   h_A (plane 0) <- embed1[src1]->dst1, embed2[src2]->dst2
//   h_B (plane 1) <- embed0[src0]->dst0, embed3[src3]->dst3
// unsafeAtomicAdd => HW global_atomic_add_f32 (no CAS loop).
// ---------------------------------------------------------------------------
__global__ void scatter_kernel(const float4* __restrict__ e0,
                               const float4* __restrict__ e1,
                               const float4* __restrict__ e2,
                               const float4* __restrict__ e3,
                               const int* __restrict__ src0,
                               const int* __restrict__ dst0,
                               const int* __restrict__ src1,
                               const int* __restrict__ dst1,
                               const int* __restrict__ src2,
                               const int* __restrict__ dst2,
                               const int* __restrict__ src3,
                               const int* __restrict__ dst3,
                               float* __restrict__ out) {
    long long t = (long long)blockIdx.x * blockDim.x + threadIdx.x;
    long long ge = t >> 4;          // global edge id across 4 relations
    int lane = (int)(t & 15);
    if (ge >= 4LL * EE) return;

    int rel = (int)(ge / EE);
    int e   = (int)(ge - (long long)rel * EE);

    const float4* emb;
    const int* src;
    const int* dst;
    float* outp;
    // rel 0 -> (embed1, src1, dst1, plane 0)
    // rel 1 -> (embed2, src2, dst2, plane 0)
    // rel 2 -> (embed0, src0, dst0, plane 1)
    // rel 3 -> (embed3, src3, dst3, plane 1)
    if (rel == 0)      { emb = e1; src = src1; dst = dst1; outp = out; }
    else if (rel == 1) { emb = e2; src = src2; dst = dst2; outp = out; }
    else if (rel == 2) { emb = e0; src = src0; dst = dst0; outp = out + ND; }
    else               { emb = e3; src = src3; dst = dst3; outp = out + ND; }

    int s = src[e];
    int d = dst[e];
    float4 v = emb[(size_t)s * 16 + lane];
    float* o = outp + (size_t)d * 64 + lane * 4;
    unsafeAtomicAdd(o + 0, v.x);
    unsafeAtomicAdd(o + 1, v.y);
    unsafeAtomicAdd(o + 2, v.z);
    unsafeAtomicAdd(o + 3, v.w);
}

// ---------------------------------------------------------------------------
// Kernel 3: in-place relu.
// ---------------------------------------------------------------------------
__global__ void relu_kernel(float4* __restrict__ out, int n4) {
    int i = blockIdx.x * blockDim.x + threadIdx.x;
    if (i < n4) {
        float4 v = out[i];
        v.x = fmaxf(v.x, 0.0f);
        v.y = fmaxf(v.y, 0.0f);
        v.z = fmaxf(v.z, 0.0f);
        v.w = fmaxf(v.w, 0.0f);
        out[i] = v;
    }
}

extern "C" void kernel_launch(void* const* d_in, const int* in_sizes, int n_in,
                              void* d_out, int out_size, void* d_ws, size_t ws_size,
                              hipStream_t stream) {
    const float4* e0 = (const float4*)d_in[0];
    const float4* e1 = (const float4*)d_in[1];
    const float4* e2 = (const float4*)d_in[2];
    const float4* e3 = (const float4*)d_in[3];
    const float4* bias4 = (const float4*)d_in[4];
    const int* src0 = (const int*)d_in[5];
    const int* dst0 = (const int*)d_in[6];
    const int* src1 = (const int*)d_in[7];
    const int* dst1 = (const int*)d_in[8];
    const int* src2 = (const int*)d_in[9];
    const int* dst2 = (const int*)d_in[10];
    const int* src3 = (const int*)d_in[11];
    const int* dst3 = (const int*)d_in[12];
    float* out = (float*)d_out;

    const int n4 = 2 * ND / 4;  // float4 count of output
    {
        int block = 256;
        int grid = (n4 + block - 1) / block;
        init_bias_kernel<<<grid, block, 0, stream>>>((float4*)out, bias4, n4);
    }
    {
        long long threads = 4LL * EE * 16;  // 16 lanes per edge
        int block = 256;
        long long grid = (threads + block - 1) / block;
        scatter_kernel<<<(int)grid, block, 0, stream>>>(
            e0, e1, e2, e3,
            src0, dst0, src1, dst1, src2, dst2, src3, dst3, out);
    }
    {
        int block = 256;
        int grid = (n4 + block - 1) / block;
        relu_kernel<<<grid, block, 0, stream>>>((float4*)out, n4);
    }
}

// Round 2
// 466.335 us; speedup vs baseline: 3.9462x; 3.9462x over previous
//
#include <hip/hip_runtime.h>

// Problem constants (match reference setup_inputs).
#define NN 100000       // nodes per ntype
#define EE 500000       // edges per etype
#define DD 64           // embed dim
#define ND (NN * DD)    // floats per ntype output plane
#define NSEG (2 * NN)   // 2 planes x NN dst nodes
#define NEDGE (4 * EE)  // total edges

// Relation mapping (reference):
//   plane 0 (h_A) <- r1: embed1[src1]->dst1 (table 0), r2: embed2[src2]->dst2 (table 1)
//   plane 1 (h_B) <- r0: embed0[src0]->dst0 (table 0), r3: embed3[src3]->dst3 (table 1)
// rel r -> (plane, table): r0->(1,0) r1->(0,0) r2->(0,1) r3->(1,1)

// ws layout (ints):
//   counts  : [0, NSEG)
//   offsets : [NSEG, 2*NSEG)
//   cursor  : [2*NSEG, 3*NSEG)
//   partials: [3*NSEG, 3*NSEG+256)
//   elist   : [3*NSEG+256, 3*NSEG+256+NEDGE)
#define WS_COUNTS   0
#define WS_OFFSETS  (NSEG)
#define WS_CURSOR   (2 * NSEG)
#define WS_PARTIALS (3 * NSEG)
#define WS_ELIST    (3 * NSEG + 256)
#define WS_INTS     (3 * NSEG + 256 + NEDGE)

#define SCAN_CHUNK 1024                      // elements per scan block (256 thr x 4)
#define SCAN_NB ((NSEG + SCAN_CHUNK - 1) / SCAN_CHUNK)  // 196

// ---------------------------------------------------------------------------
__global__ void zero_counts_kernel(int* __restrict__ counts) {
    int i = blockIdx.x * blockDim.x + threadIdx.x;
    if (i < NSEG) counts[i] = 0;
}

// ---------------------------------------------------------------------------
// Degree histogram: one thread per edge.
__global__ void count_kernel(const int* __restrict__ dst0,
                             const int* __restrict__ dst1,
                             const int* __restrict__ dst2,
                             const int* __restrict__ dst3,
                             int* __restrict__ counts) {
    int t = blockIdx.x * blockDim.x + threadIdx.x;
    if (t >= NEDGE) return;
    int r = t / EE;
    int e = t - r * EE;
    const int* dst = (r == 0) ? dst0 : (r == 1) ? dst1 : (r == 2) ? dst2 : dst3;
    int plane = (r == 1 || r == 2) ? 0 : 1;
    int idx = plane * NN + dst[e];
    atomicAdd(&counts[idx], 1);
}

// ---------------------------------------------------------------------------
// Scan pass A: per-block exclusive scan (local) + block totals.
__global__ void scanA_kernel(const int* __restrict__ counts,
                             int* __restrict__ offsets,
                             int* __restrict__ partials) {
    __shared__ int sdata[256];
    int tid = threadIdx.x;
    int base = blockIdx.x * SCAN_CHUNK + tid * 4;
    int v[4];
    int tsum = 0;
#pragma unroll
    for (int k = 0; k < 4; k++) {
        int idx = base + k;
        v[k] = (idx < NSEG) ? counts[idx] : 0;
        tsum += v[k];
    }
    sdata[tid] = tsum;
    __syncthreads();
    // Hillis-Steele inclusive scan over 256 thread sums.
    for (int off = 1; off < 256; off <<= 1) {
        int addv = (tid >= off) ? sdata[tid - off] : 0;
        __syncthreads();
        sdata[tid] += addv;
        __syncthreads();
    }
    int incl = sdata[tid];
    int excl = incl - tsum;
    int running = excl;
#pragma unroll
    for (int k = 0; k < 4; k++) {
        int idx = base + k;
        if (idx < NSEG) offsets[idx] = running;
        running += v[k];
    }
    if (tid == 255) partials[blockIdx.x] = incl;  // block total
}

// ---------------------------------------------------------------------------
// Scan pass B: exclusive scan of the <=256 block totals (single block).
__global__ void scanB_kernel(int* __restrict__ partials) {
    __shared__ int sdata[256];
    int tid = threadIdx.x;
    int v = (tid < SCAN_NB) ? partials[tid] : 0;
    sdata[tid] = v;
    __syncthreads();
    for (int off = 1; off < 256; off <<= 1) {
        int addv = (tid >= off) ? sdata[tid - off] : 0;
        __syncthreads();
        sdata[tid] += addv;
        __syncthreads();
    }
    if (tid < SCAN_NB) partials[tid] = sdata[tid] - v;  // exclusive
}

// ---------------------------------------------------------------------------
// Scan pass C: add block bases; init cursor = offsets.
__global__ void scanC_kernel(int* __restrict__ offsets,
                             const int* __restrict__ partials,
                             int* __restrict__ cursor) {
    int i = blockIdx.x * blockDim.x + threadIdx.x;
    if (i >= NSEG) return;
    int o = offsets[i] + partials[i >> 10];  // SCAN_CHUNK = 1024
    offsets[i] = o;
    cursor[i] = o;
}

// ---------------------------------------------------------------------------
// Fill: scatter edge payloads into dst-sorted edge list.
// payload = src | (table << 17)   (src < 131072)
__global__ void fill_kernel(const int* __restrict__ src0,
                            const int* __restrict__ dst0,
                            const int* __restrict__ src1,
                            const int* __restrict__ dst1,
                            const int* __restrict__ src2,
                            const int* __restrict__ dst2,
                            const int* __restrict__ src3,
                            const int* __restrict__ dst3,
                            int* __restrict__ cursor,
                            int* __restrict__ elist) {
    int t = blockIdx.x * blockDim.x + threadIdx.x;
    if (t >= NEDGE) return;
    int r = t / EE;
    int e = t - r * EE;
    const int* src;
    const int* dst;
    int plane, table;
    if (r == 0)      { src = src0; dst = dst0; plane = 1; table = 0; }
    else if (r == 1) { src = src1; dst = dst1; plane = 0; table = 0; }
    else if (r == 2) { src = src2; dst = dst2; plane = 0; table = 1; }
    else             { src = src3; dst = dst3; plane = 1; table = 1; }
    int idx = plane * NN + dst[e];
    int pos = atomicAdd(&cursor[idx], 1);
    elist[pos] = src[e] | (table << 17);
}

// ---------------------------------------------------------------------------
// Gather: one 16-lane group per (plane, dst node). acc starts at bias,
// accumulates all incoming edge rows, relu, single coalesced write.
__global__ void gather_kernel(const float4* __restrict__ e0,
                              const float4* __restrict__ e1,
                              const float4* __restrict__ e2,
                              const float4* __restrict__ e3,
                              const float4* __restrict__ bias4,
                              const int* __restrict__ offsets,
                              const int* __restrict__ counts,
                              const int* __restrict__ elist,
                              float4* __restrict__ out) {
    long long t = (long long)blockIdx.x * blockDim.x + threadIdx.x;
    long long g = t >> 4;      // segment id: plane*NN + node
    int lane = (int)(t & 15);
    if (g >= NSEG) return;

    int plane = (g >= NN) ? 1 : 0;
    const float4* tab0 = plane ? e0 : e1;
    const float4* tab1 = plane ? e3 : e2;

    int start = offsets[g];
    int cnt = counts[g];

    float4 acc = bias4[lane];
    for (int j = 0; j < cnt; j++) {
        int p = elist[start + j];
        int src = p & 0x1FFFF;
        const float4* emb = (p >> 17) ? tab1 : tab0;
        float4 v = emb[(size_t)src * 16 + lane];
        acc.x += v.x; acc.y += v.y; acc.z += v.z; acc.w += v.w;
    }
    acc.x = fmaxf(acc.x, 0.0f);
    acc.y = fmaxf(acc.y, 0.0f);
    acc.z = fmaxf(acc.z, 0.0f);
    acc.w = fmaxf(acc.w, 0.0f);
    out[g * 16 + lane] = acc;
}

// ---------------------------------------------------------------------------
// Fallback path (round-1 atomic scatter) if ws is too small.
// ---------------------------------------------------------------------------
__global__ void init_bias_kernel(float4* __restrict__ out,
                                 const float4* __restrict__ bias4,
                                 int n4) {
    int i = blockIdx.x * blockDim.x + threadIdx.x;
    if (i < n4) out[i] = bias4[i & 15];
}

__global__ void scatter_kernel(const float4* __restrict__ e0,
                               const float4* __restrict__ e1,
                               const float4* __restrict__ e2,
                               const float4* __restrict__ e3,
                               const int* __restrict__ src0,
                               const int* __restrict__ dst0,
                               const int* __restrict__ src1,
                               const int* __restrict__ dst1,
                               const int* __restrict__ src2,
                               const int* __restrict__ dst2,
                               const int* __restrict__ src3,
                               const int* __restrict__ dst3,
                               float* __restrict__ out) {
    long long t = (long long)blockIdx.x * blockDim.x + threadIdx.x;
    long long ge = t >> 4;
    int lane = (int)(t & 15);
    if (ge >= 4LL * EE) return;
    int rel = (int)(ge / EE);
    int e   = (int)(ge - (long long)rel * EE);
    const float4* emb; const int* src; const int* dst; float* outp;
    if (rel == 0)      { emb = e1; src = src1; dst = dst1; outp = out; }
    else if (rel == 1) { emb = e2; src = src2; dst = dst2; outp = out; }
    else if (rel == 2) { emb = e0; src = src0; dst = dst0; outp = out + ND; }
    else               { emb = e3; src = src3; dst = dst3; outp = out + ND; }
    int s = src[e]; int d = dst[e];
    float4 v = emb[(size_t)s * 16 + lane];
    float* o = outp + (size_t)d * 64 + lane * 4;
    unsafeAtomicAdd(o + 0, v.x);
    unsafeAtomicAdd(o + 1, v.y);
    unsafeAtomicAdd(o + 2, v.z);
    unsafeAtomicAdd(o + 3, v.w);
}

__global__ void relu_kernel(float4* __restrict__ out, int n4) {
    int i = blockIdx.x * blockDim.x + threadIdx.x;
    if (i < n4) {
        float4 v = out[i];
        v.x = fmaxf(v.x, 0.0f); v.y = fmaxf(v.y, 0.0f);
        v.z = fmaxf(v.z, 0.0f); v.w = fmaxf(v.w, 0.0f);
        out[i] = v;
    }
}

extern "C" void kernel_launch(void* const* d_in, const int* in_sizes, int n_in,
                              void* d_out, int out_size, void* d_ws, size_t ws_size,
                              hipStream_t stream) {
    const float4* e0 = (const float4*)d_in[0];
    const float4* e1 = (const float4*)d_in[1];
    const float4* e2 = (const float4*)d_in[2];
    const float4* e3 = (const float4*)d_in[3];
    const float4* bias4 = (const float4*)d_in[4];
    const int* src0 = (const int*)d_in[5];
    const int* dst0 = (const int*)d_in[6];
    const int* src1 = (const int*)d_in[7];
    const int* dst1 = (const int*)d_in[8];
    const int* src2 = (const int*)d_in[9];
    const int* dst2 = (const int*)d_in[10];
    const int* src3 = (const int*)d_in[11];
    const int* dst3 = (const int*)d_in[12];
    float* out = (float*)d_out;

    if (ws_size >= (size_t)WS_INTS * sizeof(int)) {
        int* ws = (int*)d_ws;
        int* counts   = ws + WS_COUNTS;
        int* offsets  = ws + WS_OFFSETS;
        int* cursor   = ws + WS_CURSOR;
        int* partials = ws + WS_PARTIALS;
        int* elist    = ws + WS_ELIST;

        zero_counts_kernel<<<(NSEG + 255) / 256, 256, 0, stream>>>(counts);
        count_kernel<<<(NEDGE + 255) / 256, 256, 0, stream>>>(
            dst0, dst1, dst2, dst3, counts);
        scanA_kernel<<<SCAN_NB, 256, 0, stream>>>(counts, offsets, partials);
        scanB_kernel<<<1, 256, 0, stream>>>(partials);
        scanC_kernel<<<(NSEG + 255) / 256, 256, 0, stream>>>(offsets, partials, cursor);
        fill_kernel<<<(NEDGE + 255) / 256, 256, 0, stream>>>(
            src0, dst0, src1, dst1, src2, dst2, src3, dst3, cursor, elist);
        {
            long long threads = (long long)NSEG * 16;
            int grid = (int)((threads + 255) / 256);
            gather_kernel<<<grid, 256, 0, stream>>>(
                e0, e1, e2, e3, bias4, offsets, counts, elist, (float4*)out);
        }
    } else {
        // Fallback: atomic scatter (round-1 path).
        const int n4 = 2 * ND / 4;
        init_bias_kernel<<<(n4 + 255) / 256, 256, 0, stream>>>((float4*)out, bias4, n4);
        {
            long long threads = 4LL * EE * 16;
            long long grid = (threads + 255) / 256;
            scatter_kernel<<<(int)grid, 256, 0, stream>>>(
                e0, e1, e2, e3,
                src0, dst0, src1, dst1, src2, dst2, src3, dst3, out);
        }
        relu_kernel<<<(n4 + 255) / 256, 256, 0, stream>>>((float4*)out, n4);
    }
}